// Round 14
// baseline (379.459 us; speedup 1.0000x reference)
//
#include <hip/hip_runtime.h>
#include <hip/hip_bf16.h>

#define DEV __device__ __forceinline__

typedef __bf16 bf16x8 __attribute__((ext_vector_type(8)));
typedef __bf16 bf16x2v __attribute__((ext_vector_type(2)));
typedef float f32x4 __attribute__((ext_vector_type(4)));
typedef float f32x16 __attribute__((ext_vector_type(16)));
typedef unsigned int u32;
typedef unsigned int u32x4 __attribute__((ext_vector_type(4)));
typedef __hip_bfloat16 hbf;

constexpr int Dm = 1024;
constexpr int Hh = 16;
constexpr int Ss = 2048;
constexpr int Bb = 4;
constexpr int DFm = 4096;
constexpr int LDQ = 3072;  // fused qkv row stride

DEV unsigned short f2bfu(float f) {
  hbf h = __float2bfloat16(f);
  return __builtin_bit_cast(unsigned short, h);
}

DEV float bfu2f(unsigned short u) { return __builtin_bit_cast(float, (u32)u << 16); }

DEV u32 pkbf(float x, float y) {
  bf16x2v v = {(__bf16)x, (__bf16)y};
  return __builtin_bit_cast(u32, v);
}

DEV float gelu_f(float x) {
  // 0.5x(1+tanh(z)) == x * sigmoid(2z); rcp is 1-ulp, fine for bf16-grade output
  float e = __expf(-1.5957691216057308f * (x + 0.044715f * x * x * x));
  return x * __builtin_amdgcn_rcpf(1.f + e);
}

template <int N>
DEV void s_vmcnt() {
  if constexpr (N == 0) asm volatile("s_waitcnt vmcnt(0)" ::: "memory");
  else if constexpr (N == 5) asm volatile("s_waitcnt vmcnt(5)" ::: "memory");
  else if constexpr (N == 6) asm volatile("s_waitcnt vmcnt(6)" ::: "memory");
  else if constexpr (N == 8) asm volatile("s_waitcnt vmcnt(8)" ::: "memory");
  else static_assert(N == 0, "unsupported vmcnt");
}

#define GLDS(src, dst)                                                                     \
  __builtin_amdgcn_global_load_lds((const __attribute__((address_space(1))) void*)(src),   \
                                   (__attribute__((address_space(3))) void*)(dst), 16, 0, 0)

// ---------------- all 6 weight transposes (fp32->bf16, W[K,N] -> Wt[N,K]) in one launch ---
__global__ __launch_bounds__(256) void wtransall_kernel(
    const float* __restrict__ Wq, const float* __restrict__ Wk,
    const float* __restrict__ Wv, const float* __restrict__ Wo,
    const float* __restrict__ W1, const float* __restrict__ W2,
    hbf* __restrict__ dqkv, hbf* __restrict__ dwo,
    hbf* __restrict__ dw1, hbf* __restrict__ dw2) {
  __shared__ float tile[32][33];
  const int i = blockIdx.x;
  const float* W;
  hbf* Wt;
  int K, N, k0, n0;
  if (i < 4096) {
    int z = i >> 10, j = i & 1023;
    W = z == 0 ? Wq : z == 1 ? Wk : z == 2 ? Wv : Wo;
    Wt = z == 3 ? dwo : dqkv + (size_t)z * 1024 * 1024;
    K = 1024; N = 1024; k0 = (j & 31) * 32; n0 = (j >> 5) * 32;
  } else if (i < 8192) {
    int j = i - 4096;
    W = W1; Wt = dw1; K = 1024; N = 4096;
    k0 = (j & 31) * 32; n0 = (j >> 5) * 32;
  } else {
    int j = i - 8192;
    W = W2; Wt = dw2; K = 4096; N = 1024;
    k0 = (j & 127) * 32; n0 = (j >> 7) * 32;
  }
  int tx = threadIdx.x & 31, ty = threadIdx.x >> 5;
  for (int r = ty; r < 32; r += 8) tile[r][tx] = W[(size_t)(k0 + r) * N + n0 + tx];
  __syncthreads();
  for (int r = ty; r < 32; r += 8)
    Wt[(size_t)(n0 + r) * K + k0 + tx] = __float2bfloat16(tile[tx][r]);
}

// ---------------- layernorm (fp32 or bf16 in, bf16 out), one block per row ----------------
// Row->XCD remap: block bid (XCD bid&7) handles row (bid&7)*1024 + bid>>3, so each XCD
// produces exactly the 1024-row A-slab its GEMM supertile consumes.
template <bool INBF>
__global__ __launch_bounds__(256) void ln_kernel(const void* __restrict__ xv,
                                                 const float* __restrict__ g,
                                                 const float* __restrict__ b,
                                                 hbf* __restrict__ y) {
  int row = ((blockIdx.x & 7) << 10) | (blockIdx.x >> 3);
  int t = threadIdx.x;
  float4 v;
  if constexpr (INBF) {
    ushort4 u = ((const ushort4*)((const hbf*)xv + (size_t)row * Dm))[t];
    v.x = bfu2f(u.x); v.y = bfu2f(u.y); v.z = bfu2f(u.z); v.w = bfu2f(u.w);
  } else {
    v = ((const float4*)((const float*)xv + (size_t)row * Dm))[t];
  }
  float s = v.x + v.y + v.z + v.w;
  float q = v.x * v.x + v.y * v.y + v.z * v.z + v.w * v.w;
#pragma unroll
  for (int off = 32; off > 0; off >>= 1) {
    s += __shfl_down(s, off);
    q += __shfl_down(q, off);
  }
  __shared__ float red[10];
  int wave = t >> 6, lane = t & 63;
  if (lane == 0) { red[wave] = s; red[4 + wave] = q; }
  __syncthreads();
  if (t == 0) {
    float ts = red[0] + red[1] + red[2] + red[3];
    float tq = red[4] + red[5] + red[6] + red[7];
    float mean = ts * (1.f / Dm);
    float var = tq * (1.f / Dm) - mean * mean;
    red[8] = mean;
    red[9] = rsqrtf(var + 1e-5f);
  }
  __syncthreads();
  float mean = red[8], inv = red[9];
  float4 gv = ((const float4*)g)[t];
  float4 bv = ((const float4*)b)[t];
  ushort4 o;
  o.x = f2bfu(gv.x * (v.x - mean) * inv + bv.x);
  o.y = f2bfu(gv.y * (v.y - mean) * inv + bv.y);
  o.z = f2bfu(gv.z * (v.z - mean) * inv + bv.z);
  o.w = f2bfu(gv.w * (v.w - mean) * inv + bv.w);
  ((ushort4*)(y + (size_t)row * Dm))[t] = o;
}

// ================= tiled GEMM, 2-phase schedule, 2 blocks/CU, L2-supertiled ===============
// C[M,N] = A[M,K](bf16) @ Bt[N,K]^T(bf16). BK=64. NTHR threads = WM*WN waves.
// Slabs per buffer: A-half(mh) (BM/2) rows x 64, B-half(nh) (BN/2) rows x 64 (contiguous
// 128B rows, full-cacheline gload_lds, source-chunk XOR swizzle c^(r&7), bank-conflict-free).
// NPH=2 phases per K-tile, 16 MFMA each: PA {ldAfull+ldB0, stage B1(t+1)->buf^1},
// PB {ldB1, stage A0,A1,B0(t+2)->buf, boundary vmcnt(2*ALD+BLD)}. Raw s_barrier only;
// lgkmcnt(0)+sched_barrier before MFMA (rule 18). BM=128/NTHR=256 -> LDS 64KB -> 2 blk/CU.
// Block->tile order (requires M/BM==64, (N/BN)%8==0): bid = oidx*8 + xcd; each XCD owns
// m-panels [8*xcd, 8*xcd+8) x all n-panels; oidx walks 8m x 8n supertile groups.
// C stores + residual loads are NON-TEMPORAL: stream-once data must not evict the
// L2-resident A/B panels the boundary vmcnt's stage loads depend on (R13: 700cy/phase
// unexplained stall = stage loads missing L2 due to C-write eviction).
// RES: 0 none, 1 fp32, 2 bf16.
template <int BM, int BN, int WM, int WN, int NTHR, int NPH, int ACT, bool HAS_BIAS, int RES,
          bool OUT_BF16>
__global__ __launch_bounds__(NTHR, 2) void gemm8(const hbf* __restrict__ A,
                                                 const hbf* __restrict__ Bt,
                                                 void* __restrict__ Cv,
                                                 const float* __restrict__ bias,
                                                 const void* __restrict__ resv,
                                                 int M, int N, int K) {
  constexpr int MR = (BM / WM) / 16, NR = (BN / WN) / 16;
  constexpr int MQ = MR / 2, NQ = NR / 2;
  constexpr int RPA = (BM / WM) / 2;
  constexpr int RPB = (BN / WN) / 2;
  constexpr int ASL = (BM / 2) * 64;
  constexpr int BSL = (BN / 2) * 64;
  constexpr int PERBUF = 2 * ASL + 2 * BSL;
  constexpr int ALD = ASL / (8 * NTHR);
  constexpr int BLD = BSL / (8 * NTHR);
  constexpr int VPB = 2 * ALD + BLD;        // NPH2 boundary keep-count
  constexpr int VP4 = 2 * ALD + 2 * BLD;    // NPH4 boundary keep-count

  __shared__ __align__(16) hbf lds[2 * PERBUF];

  const int tid = threadIdx.x;
  const int lane = tid & 63, wave = tid >> 6;
  const int wr = wave / WN, wc = wave % WN;
  const int lr = lane & 15, lg = lane >> 4;

  // XCD-affine supertile order (see header comment).
  const int xcd = blockIdx.x & 7, oidx = blockIdx.x >> 3;
  const int gsup = oidx >> 6, r6 = oidx & 63;
  const int m0 = (xcd * 8 + (r6 >> 3)) * BM;
  const int n0 = (gsup * 8 + (r6 & 7)) * BN;

  const hbf* Ab = A + (size_t)m0 * K;
  const hbf* Bb = Bt + (size_t)n0 * K;

  f32x4 acc[MR][NR] = {};

  auto stageA = [&](int mh, int t, int p) {
#pragma unroll
    for (int l = 0; l < ALD; ++l) {
      int ci = l * NTHR + tid;
      int r = ci >> 3, c = ci & 7;
      int piece = r / RPA, rl = r % RPA;
      int grow = piece * (BM / WM) + mh * RPA + rl;
      int gk = t * 64 + ((c ^ (r & 7)) << 3);
      GLDS(Ab + (size_t)grow * K + gk, lds + p * PERBUF + mh * ASL + (size_t)ci * 8);
    }
  };
  auto stageB = [&](int nh, int t, int p) {
#pragma unroll
    for (int l = 0; l < BLD; ++l) {
      int ci = l * NTHR + tid;
      int r = ci >> 3, c = ci & 7;
      int piece = r / RPB, rl = r % RPB;
      int grow = piece * (BN / WN) + nh * RPB + rl;
      int gk = t * 64 + ((c ^ (r & 7)) << 3);
      GLDS(Bb + (size_t)grow * K + gk, lds + p * PERBUF + 2 * ASL + nh * BSL + (size_t)ci * 8);
    }
  };
  auto ldA = [&](bf16x8 (&af)[MQ][2], int mh, int p) {
    const hbf* base = lds + p * PERBUF + mh * ASL;
#pragma unroll
    for (int i = 0; i < MQ; ++i)
#pragma unroll
      for (int ks = 0; ks < 2; ++ks) {
        int row = wr * RPA + i * 16 + lr;
        int slot = (ks * 4 + lg) ^ (lr & 7);
        af[i][ks] = *(const bf16x8*)(base + (size_t)row * 64 + slot * 8);
      }
  };
  auto ldAfull = [&](bf16x8 (&af)[MR][2], int p) {
#pragma unroll
    for (int f = 0; f < MR; ++f)
#pragma unroll
      for (int ks = 0; ks < 2; ++ks) {
        int mh = f >> 1, i = f & 1;
        const hbf* base = lds + p * PERBUF + mh * ASL;
        int row = wr * RPA + i * 16 + lr;
        int slot = (ks * 4 + lg) ^ (lr & 7);
        af[f][ks] = *(const bf16x8*)(base + (size_t)row * 64 + slot * 8);
      }
  };
  auto ldB = [&](bf16x8 (&bf)[NQ][2], int nh, int p) {
    const hbf* base = lds + p * PERBUF + 2 * ASL + nh * BSL;
#pragma unroll
    for (int j = 0; j < NQ; ++j)
#pragma unroll
      for (int ks = 0; ks < 2; ++ks) {
        int row = wc * RPB + j * 16 + lr;
        int slot = (ks * 4 + lg) ^ (lr & 7);
        bf[j][ks] = *(const bf16x8*)(base + (size_t)row * 64 + slot * 8);
      }
  };

#define SYNC_LGKM()                                        \
  do {                                                     \
    __builtin_amdgcn_s_barrier();                          \
    asm volatile("s_waitcnt lgkmcnt(0)" ::: "memory");     \
    __builtin_amdgcn_sched_barrier(0);                     \
  } while (0)

#define MFMA_Q(av, bv, mh, nh)                                                        \
  do {                                                                                \
    __builtin_amdgcn_s_setprio(1);                                                    \
    _Pragma("unroll") for (int i_ = 0; i_ < MQ; ++i_)                                 \
    _Pragma("unroll") for (int j_ = 0; j_ < NQ; ++j_)                                 \
    _Pragma("unroll") for (int k_ = 0; k_ < 2; ++k_)                                  \
      acc[(mh) * MQ + i_][(nh) * NQ + j_] = __builtin_amdgcn_mfma_f32_16x16x32_bf16(  \
          (av)[i_][k_], (bv)[j_][k_], acc[(mh) * MQ + i_][(nh) * NQ + j_], 0, 0, 0);  \
    __builtin_amdgcn_s_setprio(0);                                                    \
  } while (0)

#define MFMA_H(av, bv, nh)                                                            \
  do {                                                                                \
    __builtin_amdgcn_s_setprio(1);                                                    \
    _Pragma("unroll") for (int f_ = 0; f_ < MR; ++f_)                                 \
    _Pragma("unroll") for (int j_ = 0; j_ < NQ; ++j_)                                 \
    _Pragma("unroll") for (int k_ = 0; k_ < 2; ++k_)                                  \
      acc[f_][(nh) * NQ + j_] = __builtin_amdgcn_mfma_f32_16x16x32_bf16(              \
          (av)[f_][k_], (bv)[j_][k_], acc[f_][(nh) * NQ + j_], 0, 0, 0);              \
    __builtin_amdgcn_s_setprio(0);                                                    \
  } while (0)

  const int T = K >> 6;

  if constexpr (NPH == 4) {
    stageA(0, 0, 0); stageB(0, 0, 0); stageA(1, 0, 0); stageB(1, 0, 0);
    stageA(0, 1, 1); stageB(0, 1, 1); stageA(1, 1, 1); stageB(1, 1, 1);
    s_vmcnt<VP4>();
    __builtin_amdgcn_s_barrier();

    for (int t = 0; t < T; ++t) {
      const int p = t & 1;
      bf16x8 a0[MQ][2], a1[MQ][2], b0[NQ][2], b1[NQ][2];
      ldA(a0, 0, p);
      ldB(b0, 0, p);
      asm volatile("s_waitcnt lgkmcnt(8)" ::: "memory");
      SYNC_LGKM();
      MFMA_Q(a0, b0, 0, 0);
      __builtin_amdgcn_s_barrier();
      ldA(a1, 1, p);
      if (t + 2 < T) { stageA(0, t + 2, p); stageB(0, t + 2, p); }
      SYNC_LGKM();
      MFMA_Q(a1, b0, 1, 0);
      __builtin_amdgcn_s_barrier();
      ldB(b1, 1, p);
      if (t + 2 < T) stageA(1, t + 2, p);
      SYNC_LGKM();
      MFMA_Q(a1, b1, 1, 1);
      __builtin_amdgcn_s_barrier();
      if (t + 2 < T) stageB(1, t + 2, p);
      MFMA_Q(a0, b1, 0, 1);
      if (t + 1 < T) {
        if (t + 2 < T) s_vmcnt<VP4>();
        else s_vmcnt<0>();
      }
      __builtin_amdgcn_s_barrier();
    }
  } else {
    // NPH==2: prologue = tile0 full, tile1 minus B1; keep tile1's VPB
    stageA(0, 0, 0); stageA(1, 0, 0); stageB(0, 0, 0); stageB(1, 0, 0);
    stageA(0, 1, 1); stageA(1, 1, 1); stageB(0, 1, 1);
    s_vmcnt<VPB>();
    __builtin_amdgcn_s_barrier();

    for (int t = 0; t < T; ++t) {
      const int p = t & 1;
      bf16x8 af[MR][2], b0[NQ][2], b1[NQ][2];
      // PA: all-A x nh0; stage B1(t+1) -> buf p^1
      ldAfull(af, p);
      ldB(b0, 0, p);
      if (t + 1 < T) stageB(1, t + 1, p ^ 1);
      asm volatile("s_waitcnt lgkmcnt(8)" ::: "memory");
      SYNC_LGKM();
      MFMA_H(af, b0, 0);
      __builtin_amdgcn_s_barrier();
      // PB: all-A x nh1; stage A0,A1,B0(t+2) -> buf p; boundary vmcnt
      ldB(b1, 1, p);
      if (t + 2 < T) { stageA(0, t + 2, p); stageA(1, t + 2, p); stageB(0, t + 2, p); }
      SYNC_LGKM();
      MFMA_H(af, b1, 1);
      if (t + 1 < T) {
        if (t + 2 < T) s_vmcnt<VPB>();
        else s_vmcnt<0>();
      }
      __builtin_amdgcn_s_barrier();
    }
  }
#undef SYNC_LGKM
#undef MFMA_Q
#undef MFMA_H

  // ---- epilogue: non-temporal residual loads + non-temporal C stores ----
#pragma unroll
  for (int mf = 0; mf < MR; ++mf) {
    int row = m0 + wr * (BM / WM) + mf * 16 + lg * 4;
#pragma unroll
    for (int n = 0; n < NR; ++n) {
      int col = n0 + wc * (BN / WN) + n * 16 + lr;
      float bvl = HAS_BIAS ? bias[col] : 0.f;
#pragma unroll
      for (int j = 0; j < 4; ++j) {
        float v = acc[mf][n][j] + bvl;
        if (ACT == 1) v = gelu_f(v);
        if constexpr (RES == 1)
          v += __builtin_nontemporal_load(&((const float*)resv)[(size_t)(row + j) * N + col]);
        else if constexpr (RES == 2)
          v += bfu2f(__builtin_nontemporal_load(
              &((const unsigned short*)resv)[(size_t)(row + j) * N + col]));
        if (OUT_BF16)
          __builtin_nontemporal_store(f2bfu(v),
                                      &((unsigned short*)Cv)[(size_t)(row + j) * N + col]);
        else
          __builtin_nontemporal_store(v, &((float*)Cv)[(size_t)(row + j) * N + col]);
      }
    }
  }
}

// ---------------- per-head V transpose: qkv[b,s,2048+h*64+d] -> vt[(b*H+h)*64+d, s] -------
__global__ __launch_bounds__(256) void vtrans_kernel(const hbf* __restrict__ qkv,
                                                     hbf* __restrict__ vt) {
  __shared__ unsigned short tile[64][65];
  int bh = blockIdx.y, b = bh >> 4, hh = bh & 15;
  int s0 = blockIdx.x * 64;
  int d = threadIdx.x & 63, r0 = threadIdx.x >> 6;
#pragma unroll
  for (int i = 0; i < 16; ++i) {
    int r = r0 * 16 + i;
    tile[d][r] = __builtin_bit_cast(unsigned short,
                                    qkv[(size_t)(b * Ss + s0 + r) * LDQ + 2048 + hh * 64 + d]);
  }
  __syncthreads();
#pragma unroll
  for (int i = 0; i < 16; ++i) {
    int r = r0 * 16 + i;
    vt[(size_t)(bh * 64 + r) * Ss + s0 + d] = __builtin_bit_cast(hbf, tile[r][d]);
  }
}

// ---------------- causal flash attention, swapped QK^T, in-register softmax ---------------
// Grid 1024: xcd = gi&7 owns heads {bh: bh&7==xcd} (8 heads x 16 q-blocks, 4MB K/V = L2).
// Per-XCD dispatch rank kk>>3 orders blocks heavy-first ACROSS heads.
__global__ __launch_bounds__(256, 3) void attn_kernel(const hbf* __restrict__ qkv,
                                                      const hbf* __restrict__ vt,
                                                      hbf* __restrict__ ctx) {
  __shared__ __align__(16) hbf Ks[2][64 * 64];
  __shared__ __align__(16) hbf Vs[2][64 * 64];

  const int tid = threadIdx.x;
  const int wave = tid >> 6, lane = tid & 63;
  const int l31 = lane & 31, hi = lane >> 5;

  const int gi = blockIdx.x;
  const int xslot = gi & 7, kk = gi >> 3;
  const int rank = kk >> 3, hg = kk & 7;
  const int bh = hg * 8 + xslot;
  const int bx = 15 - rank;
  const int b = bh >> 4, hh = bh & 15;
  const int q0b = bx * 128;
  const int q0w = q0b + wave * 32;
  const int nsteps = (q0b + 128) >> 6;
  const int my_steps = (q0w + 95) >> 6;

  constexpr float QSCALE = 0.18033688011112042f;  // 0.125 * log2(e)
  bf16x8 qf[4];
  {
    const hbf* qrow = qkv + (size_t)(b * Ss + q0w + l31) * LDQ + hh * 64 + hi * 8;
#pragma unroll
    for (int ds = 0; ds < 4; ++ds) {
      bf16x8 t = *(const bf16x8*)(qrow + ds * 16);
#pragma unroll
      for (int e = 0; e < 8; ++e) qf[ds][e] = (__bf16)((float)t[e] * QSCALE);
    }
  }

  const hbf* kbase = qkv + 1024 + (size_t)(b * Ss) * LDQ + hh * 64;
  const hbf* vbase = vt + (size_t)(bh * 64) * Ss;
  const int i0 = tid, i1 = tid + 256;
  const int r0 = i0 >> 3, s0c = (i0 & 7), r1 = i1 >> 3, s1c = (i1 & 7);
  const int c0 = 8 * (s0c ^ (r0 & 7)), c1 = 8 * (s1c ^ (r1 & 7));

  f32x16 ot[2] = {};
  float m_run = -1e30f, l_run = 0.f;

  {
    hbf* kd = &Ks[0][0];
    hbf* vd = &Vs[0][0];
    GLDS(kbase + (size_t)r0 * LDQ + c0, kd + i0 * 8);
    GLDS(kbase + (size_t)r1 * LDQ + c1, kd + i1 * 8);
    GLDS(vbase + (size_t)r0 * Ss + c0, vd + i0 * 8);
    GLDS(vbase + (size_t)r1 * Ss + c1, vd + i1 * 8);
  }
  __syncthreads();

  int buf = 0;
  for (int it = 0; it < nsteps; ++it) {
    const int k0 = it << 6;
    if (it + 1 < nsteps) {
      hbf* kd = &Ks[buf ^ 1][0];
      hbf* vd = &Vs[buf ^ 1][0];
      GLDS(kbase + (size_t)(k0 + 64 + r0) * LDQ + c0, kd + i0 * 8);
      GLDS(kbase + (size_t)(k0 + 64 + r1) * LDQ + c1, kd + i1 * 8);
      GLDS(vbase + (size_t)r0 * Ss + k0 + 64 + c0, vd + i0 * 8);
      GLDS(vbase + (size_t)r1 * Ss + k0 + 64 + c1, vd + i1 * 8);
    }

    if (it < my_steps) {
      const hbf* kt = &Ks[buf][0];
      f32x16 st[2] = {};
      __builtin_amdgcn_s_setprio(1);
#pragma unroll
      for (int c = 0; c < 2; ++c) {
        const int krow = l31 + 32 * c;
        const int kr7 = krow & 7;
#pragma unroll
        for (int ds = 0; ds < 4; ++ds) {
          bf16x8 kf = *(const bf16x8*)(kt + krow * 64 + 8 * ((ds * 2 + hi) ^ kr7));
          st[c] = __builtin_amdgcn_mfma_f32_32x32x16_bf16(kf, qf[ds], st[c], 0, 0, 0);
        }
      }
      __builtin_amdgcn_s_setprio(0);

      if (it == my_steps - 1) {
        const int qg = q0w + l31;
#pragma unroll
        for (int c = 0; c < 2; ++c)
#pragma unroll
          for (int rg = 0; rg < 16; ++rg) {
            int kg = k0 + c * 32 + (rg & 3) + 8 * (rg >> 2) + 4 * hi;
            if (kg > qg) st[c][rg] = -3e38f;
          }
      }

      // row max: in-lane 32 + cross-half via shfl (R6-proven)
      float mx = -3e38f;
#pragma unroll
      for (int c = 0; c < 2; ++c)
#pragma unroll
        for (int rg = 0; rg < 16; ++rg) mx = fmaxf(mx, st[c][rg]);
      mx = fmaxf(mx, __shfl_xor(mx, 32));
      if (!__all(mx - m_run <= 11.541560327111707f)) {
        float mn = fmaxf(m_run, mx);
        float sc = exp2f(m_run - mn);
        m_run = mn;
        l_run *= sc;
#pragma unroll
        for (int dc = 0; dc < 2; ++dc)
#pragma unroll
          for (int rg = 0; rg < 16; ++rg) ot[dc][rg] *= sc;
      }
      float rs = 0.f;
#pragma unroll
      for (int c = 0; c < 2; ++c)
#pragma unroll
        for (int rg = 0; rg < 16; ++rg) {
          float p = exp2f(st[c][rg] - m_run);
          st[c][rg] = p;
          rs += p;
        }
      rs += __shfl_xor(rs, 32);
      l_run += rs;

      // P repack (R6-proven shfl+select form)
      bf16x8 pf[2][2];
#pragma unroll
      for (int c = 0; c < 2; ++c)
#pragma unroll
        for (int ks = 0; ks < 2; ++ks) {
          const int rb = ks * 8;
          u32 a0 = pkbf(st[c][rb + 0], st[c][rb + 1]);
          u32 a1 = pkbf(st[c][rb + 2], st[c][rb + 3]);
          u32 b0 = pkbf(st[c][rb + 4], st[c][rb + 5]);
          u32 b1 = pkbf(st[c][rb + 6], st[c][rb + 7]);
          u32 pa0 = __shfl_xor(a0, 32), pa1 = __shfl_xor(a1, 32);
          u32 pb0 = __shfl_xor(b0, 32), pb1 = __shfl_xor(b1, 32);
          u32x4 f;
          f.x = hi ? pb0 : a0;
          f.y = hi ? pb1 : a1;
          f.z = hi ? b0 : pa0;
          f.w = hi ? b1 : pa1;
          pf[c][ks] = __builtin_bit_cast(bf16x8, f);
        }

      const hbf* vtl = &Vs[buf][0];
      __builtin_amdgcn_s_setprio(1);
#pragma unroll
      for (int dc = 0; dc < 2; ++dc) {
        const int vrow = l31 + 32 * dc;
        const int vr7 = vrow & 7;
#pragma unroll
        for (int c = 0; c < 2; ++c)
#pragma unroll
          for (int ks = 0; ks < 2; ++ks) {
            bf16x8 vf = *(const bf16x8*)(vtl + vrow * 64 + 8 * ((c * 4 + ks * 2 + hi) ^ vr7));
            ot[dc] = __builtin_amdgcn_mfma_f32_32x32x16_bf16(vf, pf[c][ks], ot[dc], 0, 0, 0);
          }
      }
      __builtin_amdgcn_s_setprio(0);
    }

    __syncthreads();
    buf ^= 1;
  }

  const float inv = __builtin_amdgcn_rcpf(l_run);
  hbf* crow = ctx + (size_t)(b * Ss + q0w + l31) * Dm + hh * 64;
#pragma unroll
  for (int dc = 0; dc < 2; ++dc)
#pragma unroll
    for (int rg = 0; rg < 4; ++rg) {
      ushort4 w;
      w.x = f2bfu(ot[dc][rg * 4 + 0] * inv);
      w.y = f2bfu(ot[dc][rg * 4 + 1] * inv);
      w.z = f2bfu(ot[dc][rg * 4 + 2] * inv);
      w.w = f2bfu(ot[dc][rg * 4 + 3] * inv);
      *(ushort4*)(crow + dc * 32 + rg * 8 + hi * 4) = w;
    }
}

// -----------------------------------------------------------------------------------------
extern "C" void kernel_launch(void* const* d_in, const int* in_sizes, int n_in,
                              void* d_out, int out_size, void* d_ws, size_t ws_size,
                              hipStream_t stream) {
  const float* x  = (const float*)d_in[0];
  const float* Wq = (const float*)d_in[1];
  const float* Wk = (const float*)d_in[2];
  const float* Wv = (const float*)d_in[3];
  const float* Wo = (const float*)d_in[4];
  const float* bo = (const float*)d_in[5];
  const float* W1 = (const float*)d_in[6];
  const float* b1 = (const float*)d_in[7];
  const float* W2 = (const float*)d_in[8];
  const float* b2 = (const float*)d_in[9];
  const float* g1 = (const float*)d_in[10];
  const float* s1 = (const float*)d_in[11];
  const float* g2 = (const float*)d_in[12];
  const float* s2 = (const float*)d_in[13];
  float* out = (float*)d_out;

  char* ws = (char*)d_ws;
  constexpr size_t MB = 1024ull * 1024ull;
  hbf* wqkvT = (hbf*)(ws + 0 * MB);    // 6MB [3072][1024]
  hbf* woT   = (hbf*)(ws + 6 * MB);    // 2MB
  hbf* w1T   = (hbf*)(ws + 8 * MB);    // 8MB
  hbf* w2T   = (hbf*)(ws + 16 * MB);   // 8MB
  hbf* xln   = (hbf*)(ws + 24 * MB);   // 16MB (reused: ctx, then y2)
  hbf* ctx   = (hbf*)(ws + 24 * MB);
  hbf* y2    = (hbf*)(ws + 24 * MB);
  hbf* qkvb  = (hbf*)(ws + 40 * MB);   // 48MB [8192][3072]
  hbf* vtb   = (hbf*)(ws + 88 * MB);   // 16MB
  hbf* ff1   = (hbf*)(ws + 40 * MB);   // 64MB (over dead qkv/vt)
  hbf* hbb   = (hbf*)(ws + 104 * MB);  // 16MB bf16 residual trunk
  (void)ws_size; (void)in_sizes; (void)n_in; (void)out_size;

  const int BS = Bb * Ss;  // 8192 rows

  // 1) all weights -> bf16 transposed [N,K] (one launch)
  wtransall_kernel<<<12288, 256, 0, stream>>>(Wq, Wk, Wv, Wo, W1, W2,
                                              wqkvT, woT, w1T, w2T);

  // 2) LN1
  ln_kernel<false><<<BS, 256, 0, stream>>>(x, g1, s1, xln);

  // 3) fused QKV projection: [8192,1024] @ [1024,3072]  (grid 64x24=1536, 2 blk/CU)
  gemm8<128, 128, 2, 2, 256, 2, 0, false, 0, true><<<1536, 256, 0, stream>>>(
      xln, wqkvT, qkvb, nullptr, nullptr, BS, LDQ, Dm);

  // 4) V transpose per head
  vtrans_kernel<<<dim3(Ss / 64, Bb * Hh), 256, 0, stream>>>(qkvb, vtb);

  // 5) flash attention
  attn_kernel<<<dim3(1024), 256, 0, stream>>>(qkvb, vtb, ctx);

  // 6) output projection + bias + residual(x fp32) -> h (bf16)  (grid 512)
  gemm8<128, 128, 2, 2, 256, 2, 0, true, 1, true><<<512, 256, 0, stream>>>(
      ctx, woT, hbb, bo, x, BS, Dm, Dm);

  // 7) LN2 (bf16 in)
  ln_kernel<true><<<BS, 256, 0, stream>>>(hbb, g2, s2, y2);

  // 8) FF1 + bias + GELU  (grid 64x32=2048)
  gemm8<128, 128, 2, 2, 256, 2, 1, true, 0, true><<<2048, 256, 0, stream>>>(
      y2, w1T, ff1, b1, nullptr, BS, DFm, Dm);

  // 9) FF2 + bias + residual(h bf16) -> out (fp32)  (grid 512, K=4096)
  gemm8<128, 128, 2, 2, 256, 2, 0, true, 2, false><<<512, 256, 0, stream>>>(
      ff1, w2T, out, b2, hbb, BS, Dm, DFm);
}

// Round 15
// 343.863 us; speedup vs baseline: 1.1035x; 1.1035x over previous
//
#include <hip/hip_runtime.h>
#include <hip/hip_bf16.h>

#define DEV __device__ __forceinline__

typedef __bf16 bf16x8 __attribute__((ext_vector_type(8)));
typedef __bf16 bf16x2v __attribute__((ext_vector_type(2)));
typedef float f32x4 __attribute__((ext_vector_type(4)));
typedef float f32x16 __attribute__((ext_vector_type(16)));
typedef unsigned int u32;
typedef unsigned int u32x4 __attribute__((ext_vector_type(4)));
typedef __hip_bfloat16 hbf;

constexpr int Dm = 1024;
constexpr int Hh = 16;
constexpr int Ss = 2048;
constexpr int Bb = 4;
constexpr int DFm = 4096;
constexpr int LDQ = 3072;  // fused qkv row stride

DEV unsigned short f2bfu(float f) {
  hbf h = __float2bfloat16(f);
  return __builtin_bit_cast(unsigned short, h);
}

DEV float bfu2f(unsigned short u) { return __builtin_bit_cast(float, (u32)u << 16); }

DEV u32 pkbf(float x, float y) {
  bf16x2v v = {(__bf16)x, (__bf16)y};
  return __builtin_bit_cast(u32, v);
}

DEV float gelu_f(float x) {
  // 0.5x(1+tanh(z)) == x * sigmoid(2z); rcp is 1-ulp, fine for bf16-grade output
  float e = __expf(-1.5957691216057308f * (x + 0.044715f * x * x * x));
  return x * __builtin_amdgcn_rcpf(1.f + e);
}

template <int N>
DEV void s_vmcnt() {
  if constexpr (N == 0) asm volatile("s_waitcnt vmcnt(0)" ::: "memory");
  else if constexpr (N == 5) asm volatile("s_waitcnt vmcnt(5)" ::: "memory");
  else if constexpr (N == 6) asm volatile("s_waitcnt vmcnt(6)" ::: "memory");
  else if constexpr (N == 8) asm volatile("s_waitcnt vmcnt(8)" ::: "memory");
  else static_assert(N == 0, "unsupported vmcnt");
}

#define GLDS(src, dst)                                                                     \
  __builtin_amdgcn_global_load_lds((const __attribute__((address_space(1))) void*)(src),   \
                                   (__attribute__((address_space(3))) void*)(dst), 16, 0, 0)

// ---------------- all 6 weight transposes (fp32->bf16, W[K,N] -> Wt[N,K]) in one launch ---
__global__ __launch_bounds__(256) void wtransall_kernel(
    const float* __restrict__ Wq, const float* __restrict__ Wk,
    const float* __restrict__ Wv, const float* __restrict__ Wo,
    const float* __restrict__ W1, const float* __restrict__ W2,
    hbf* __restrict__ dqkv, hbf* __restrict__ dwo,
    hbf* __restrict__ dw1, hbf* __restrict__ dw2) {
  __shared__ float tile[32][33];
  const int i = blockIdx.x;
  const float* W;
  hbf* Wt;
  int K, N, k0, n0;
  if (i < 4096) {
    int z = i >> 10, j = i & 1023;
    W = z == 0 ? Wq : z == 1 ? Wk : z == 2 ? Wv : Wo;
    Wt = z == 3 ? dwo : dqkv + (size_t)z * 1024 * 1024;
    K = 1024; N = 1024; k0 = (j & 31) * 32; n0 = (j >> 5) * 32;
  } else if (i < 8192) {
    int j = i - 4096;
    W = W1; Wt = dw1; K = 1024; N = 4096;
    k0 = (j & 31) * 32; n0 = (j >> 5) * 32;
  } else {
    int j = i - 8192;
    W = W2; Wt = dw2; K = 4096; N = 1024;
    k0 = (j & 127) * 32; n0 = (j >> 7) * 32;
  }
  int tx = threadIdx.x & 31, ty = threadIdx.x >> 5;
  for (int r = ty; r < 32; r += 8) tile[r][tx] = W[(size_t)(k0 + r) * N + n0 + tx];
  __syncthreads();
  for (int r = ty; r < 32; r += 8)
    Wt[(size_t)(n0 + r) * K + k0 + tx] = __float2bfloat16(tile[tx][r]);
}

// ---------------- layernorm (fp32 or bf16 in, bf16 out), one block per row ----------------
// Row->XCD remap: block bid (XCD bid&7) handles row (bid&7)*1024 + bid>>3, so each XCD
// produces exactly the 1024-row A-slab its GEMM supertile consumes.
template <bool INBF>
__global__ __launch_bounds__(256) void ln_kernel(const void* __restrict__ xv,
                                                 const float* __restrict__ g,
                                                 const float* __restrict__ b,
                                                 hbf* __restrict__ y) {
  int row = ((blockIdx.x & 7) << 10) | (blockIdx.x >> 3);
  int t = threadIdx.x;
  float4 v;
  if constexpr (INBF) {
    ushort4 u = ((const ushort4*)((const hbf*)xv + (size_t)row * Dm))[t];
    v.x = bfu2f(u.x); v.y = bfu2f(u.y); v.z = bfu2f(u.z); v.w = bfu2f(u.w);
  } else {
    v = ((const float4*)((const float*)xv + (size_t)row * Dm))[t];
  }
  float s = v.x + v.y + v.z + v.w;
  float q = v.x * v.x + v.y * v.y + v.z * v.z + v.w * v.w;
#pragma unroll
  for (int off = 32; off > 0; off >>= 1) {
    s += __shfl_down(s, off);
    q += __shfl_down(q, off);
  }
  __shared__ float red[10];
  int wave = t >> 6, lane = t & 63;
  if (lane == 0) { red[wave] = s; red[4 + wave] = q; }
  __syncthreads();
  if (t == 0) {
    float ts = red[0] + red[1] + red[2] + red[3];
    float tq = red[4] + red[5] + red[6] + red[7];
    float mean = ts * (1.f / Dm);
    float var = tq * (1.f / Dm) - mean * mean;
    red[8] = mean;
    red[9] = rsqrtf(var + 1e-5f);
  }
  __syncthreads();
  float mean = red[8], inv = red[9];
  float4 gv = ((const float4*)g)[t];
  float4 bv = ((const float4*)b)[t];
  ushort4 o;
  o.x = f2bfu(gv.x * (v.x - mean) * inv + bv.x);
  o.y = f2bfu(gv.y * (v.y - mean) * inv + bv.y);
  o.z = f2bfu(gv.z * (v.z - mean) * inv + bv.z);
  o.w = f2bfu(gv.w * (v.w - mean) * inv + bv.w);
  ((ushort4*)(y + (size_t)row * Dm))[t] = o;
}

// ================= tiled GEMM, 2-phase schedule, 2 blocks/CU, L2-supertiled ===============
// C[M,N] = A[M,K](bf16) @ Bt[N,K]^T(bf16). BK=64. NTHR threads = WM*WN waves.
// Slabs per buffer: A-half(mh) (BM/2) rows x 64, B-half(nh) (BN/2) rows x 64 (contiguous
// 128B rows, full-cacheline gload_lds, source-chunk XOR swizzle c^(r&7), bank-conflict-free).
// NPH=2 phases per K-tile, 16 MFMA each: PA {ldAfull+ldB0, stage B1(t+1)->buf^1},
// PB {ldB1, stage A0,A1,B0(t+2)->buf, boundary vmcnt(2*ALD+BLD)}. Raw s_barrier only;
// lgkmcnt(0)+sched_barrier before MFMA (rule 18). BM=128/NTHR=256 -> LDS 64KB -> 2 blk/CU.
// Block->tile order (requires M/BM==64, (N/BN)%8==0): bid = oidx*8 + xcd; each XCD owns
// m-panels [8*xcd, 8*xcd+8) x all n-panels; oidx walks 8m x 8n supertile groups so the ~64
// concurrently-resident blocks per XCD share a <=4MB (K=1024) L2-resident A+B set.
// Plain (cached) epilogue loads/stores — R14's non-temporal variant regressed 11%:
// nt bypasses L2 so consumers of C refetch from HBM; eviction cost < latency cost.
// RES: 0 none, 1 fp32, 2 bf16.
template <int BM, int BN, int WM, int WN, int NTHR, int NPH, int ACT, bool HAS_BIAS, int RES,
          bool OUT_BF16>
__global__ __launch_bounds__(NTHR, 2) void gemm8(const hbf* __restrict__ A,
                                                 const hbf* __restrict__ Bt,
                                                 void* __restrict__ Cv,
                                                 const float* __restrict__ bias,
                                                 const void* __restrict__ resv,
                                                 int M, int N, int K) {
  constexpr int MR = (BM / WM) / 16, NR = (BN / WN) / 16;
  constexpr int MQ = MR / 2, NQ = NR / 2;
  constexpr int RPA = (BM / WM) / 2;
  constexpr int RPB = (BN / WN) / 2;
  constexpr int ASL = (BM / 2) * 64;
  constexpr int BSL = (BN / 2) * 64;
  constexpr int PERBUF = 2 * ASL + 2 * BSL;
  constexpr int ALD = ASL / (8 * NTHR);
  constexpr int BLD = BSL / (8 * NTHR);
  constexpr int VPB = 2 * ALD + BLD;        // NPH2 boundary keep-count
  constexpr int VP4 = 2 * ALD + 2 * BLD;    // NPH4 boundary keep-count

  __shared__ __align__(16) hbf lds[2 * PERBUF];

  const int tid = threadIdx.x;
  const int lane = tid & 63, wave = tid >> 6;
  const int wr = wave / WN, wc = wave % WN;
  const int lr = lane & 15, lg = lane >> 4;

  // XCD-affine supertile order (see header comment).
  const int xcd = blockIdx.x & 7, oidx = blockIdx.x >> 3;
  const int gsup = oidx >> 6, r6 = oidx & 63;
  const int m0 = (xcd * 8 + (r6 >> 3)) * BM;
  const int n0 = (gsup * 8 + (r6 & 7)) * BN;

  const hbf* Ab = A + (size_t)m0 * K;
  const hbf* Bb = Bt + (size_t)n0 * K;

  f32x4 acc[MR][NR] = {};

  auto stageA = [&](int mh, int t, int p) {
#pragma unroll
    for (int l = 0; l < ALD; ++l) {
      int ci = l * NTHR + tid;
      int r = ci >> 3, c = ci & 7;
      int piece = r / RPA, rl = r % RPA;
      int grow = piece * (BM / WM) + mh * RPA + rl;
      int gk = t * 64 + ((c ^ (r & 7)) << 3);
      GLDS(Ab + (size_t)grow * K + gk, lds + p * PERBUF + mh * ASL + (size_t)ci * 8);
    }
  };
  auto stageB = [&](int nh, int t, int p) {
#pragma unroll
    for (int l = 0; l < BLD; ++l) {
      int ci = l * NTHR + tid;
      int r = ci >> 3, c = ci & 7;
      int piece = r / RPB, rl = r % RPB;
      int grow = piece * (BN / WN) + nh * RPB + rl;
      int gk = t * 64 + ((c ^ (r & 7)) << 3);
      GLDS(Bb + (size_t)grow * K + gk, lds + p * PERBUF + 2 * ASL + nh * BSL + (size_t)ci * 8);
    }
  };
  auto ldA = [&](bf16x8 (&af)[MQ][2], int mh, int p) {
    const hbf* base = lds + p * PERBUF + mh * ASL;
#pragma unroll
    for (int i = 0; i < MQ; ++i)
#pragma unroll
      for (int ks = 0; ks < 2; ++ks) {
        int row = wr * RPA + i * 16 + lr;
        int slot = (ks * 4 + lg) ^ (lr & 7);
        af[i][ks] = *(const bf16x8*)(base + (size_t)row * 64 + slot * 8);
      }
  };
  auto ldAfull = [&](bf16x8 (&af)[MR][2], int p) {
#pragma unroll
    for (int f = 0; f < MR; ++f)
#pragma unroll
      for (int ks = 0; ks < 2; ++ks) {
        int mh = f >> 1, i = f & 1;
        const hbf* base = lds + p * PERBUF + mh * ASL;
        int row = wr * RPA + i * 16 + lr;
        int slot = (ks * 4 + lg) ^ (lr & 7);
        af[f][ks] = *(const bf16x8*)(base + (size_t)row * 64 + slot * 8);
      }
  };
  auto ldB = [&](bf16x8 (&bf)[NQ][2], int nh, int p) {
    const hbf* base = lds + p * PERBUF + 2 * ASL + nh * BSL;
#pragma unroll
    for (int j = 0; j < NQ; ++j)
#pragma unroll
      for (int ks = 0; ks < 2; ++ks) {
        int row = wc * RPB + j * 16 + lr;
        int slot = (ks * 4 + lg) ^ (lr & 7);
        bf[j][ks] = *(const bf16x8*)(base + (size_t)row * 64 + slot * 8);
      }
  };

#define SYNC_LGKM()                                        \
  do {                                                     \
    __builtin_amdgcn_s_barrier();                          \
    asm volatile("s_waitcnt lgkmcnt(0)" ::: "memory");     \
    __builtin_amdgcn_sched_barrier(0);                     \
  } while (0)

#define MFMA_Q(av, bv, mh, nh)                                                        \
  do {                                                                                \
    __builtin_amdgcn_s_setprio(1);                                                    \
    _Pragma("unroll") for (int i_ = 0; i_ < MQ; ++i_)                                 \
    _Pragma("unroll") for (int j_ = 0; j_ < NQ; ++j_)                                 \
    _Pragma("unroll") for (int k_ = 0; k_ < 2; ++k_)                                  \
      acc[(mh) * MQ + i_][(nh) * NQ + j_] = __builtin_amdgcn_mfma_f32_16x16x32_bf16(  \
          (av)[i_][k_], (bv)[j_][k_], acc[(mh) * MQ + i_][(nh) * NQ + j_], 0, 0, 0);  \
    __builtin_amdgcn_s_setprio(0);                                                    \
  } while (0)

#define MFMA_H(av, bv, nh)                                                            \
  do {                                                                                \
    __builtin_amdgcn_s_setprio(1);                                                    \
    _Pragma("unroll") for (int f_ = 0; f_ < MR; ++f_)                                 \
    _Pragma("unroll") for (int j_ = 0; j_ < NQ; ++j_)                                 \
    _Pragma("unroll") for (int k_ = 0; k_ < 2; ++k_)                                  \
      acc[f_][(nh) * NQ + j_] = __builtin_amdgcn_mfma_f32_16x16x32_bf16(              \
          (av)[f_][k_], (bv)[j_][k_], acc[f_][(nh) * NQ + j_], 0, 0, 0);              \
    __builtin_amdgcn_s_setprio(0);                                                    \
  } while (0)

  const int T = K >> 6;

  if constexpr (NPH == 4) {
    stageA(0, 0, 0); stageB(0, 0, 0); stageA(1, 0, 0); stageB(1, 0, 0);
    stageA(0, 1, 1); stageB(0, 1, 1); stageA(1, 1, 1); stageB(1, 1, 1);
    s_vmcnt<VP4>();
    __builtin_amdgcn_s_barrier();

    for (int t = 0; t < T; ++t) {
      const int p = t & 1;
      bf16x8 a0[MQ][2], a1[MQ][2], b0[NQ][2], b1[NQ][2];
      ldA(a0, 0, p);
      ldB(b0, 0, p);
      asm volatile("s_waitcnt lgkmcnt(8)" ::: "memory");
      SYNC_LGKM();
      MFMA_Q(a0, b0, 0, 0);
      __builtin_amdgcn_s_barrier();
      ldA(a1, 1, p);
      if (t + 2 < T) { stageA(0, t + 2, p); stageB(0, t + 2, p); }
      SYNC_LGKM();
      MFMA_Q(a1, b0, 1, 0);
      __builtin_amdgcn_s_barrier();
      ldB(b1, 1, p);
      if (t + 2 < T) stageA(1, t + 2, p);
      SYNC_LGKM();
      MFMA_Q(a1, b1, 1, 1);
      __builtin_amdgcn_s_barrier();
      if (t + 2 < T) stageB(1, t + 2, p);
      MFMA_Q(a0, b1, 0, 1);
      if (t + 1 < T) {
        if (t + 2 < T) s_vmcnt<VP4>();
        else s_vmcnt<0>();
      }
      __builtin_amdgcn_s_barrier();
    }
  } else {
    // NPH==2: prologue = tile0 full, tile1 minus B1; keep tile1's VPB
    stageA(0, 0, 0); stageA(1, 0, 0); stageB(0, 0, 0); stageB(1, 0, 0);
    stageA(0, 1, 1); stageA(1, 1, 1); stageB(0, 1, 1);
    s_vmcnt<VPB>();
    __builtin_amdgcn_s_barrier();

    for (int t = 0; t < T; ++t) {
      const int p = t & 1;
      bf16x8 af[MR][2], b0[NQ][2], b1[NQ][2];
      // PA: all-A x nh0; stage B1(t+1) -> buf p^1
      ldAfull(af, p);
      ldB(b0, 0, p);
      if (t + 1 < T) stageB(1, t + 1, p ^ 1);
      asm volatile("s_waitcnt lgkmcnt(8)" ::: "memory");
      SYNC_LGKM();
      MFMA_H(af, b0, 0);
      __builtin_amdgcn_s_barrier();
      // PB: all-A x nh1; stage A0,A1,B0(t+2) -> buf p; boundary vmcnt
      ldB(b1, 1, p);
      if (t + 2 < T) { stageA(0, t + 2, p); stageA(1, t + 2, p); stageB(0, t + 2, p); }
      SYNC_LGKM();
      MFMA_H(af, b1, 1);
      if (t + 1 < T) {
        if (t + 2 < T) s_vmcnt<VPB>();
        else s_vmcnt<0>();
      }
      __builtin_amdgcn_s_barrier();
    }
  }
#undef SYNC_LGKM
#undef MFMA_Q
#undef MFMA_H

  // ---- epilogue (plain cached loads/stores) ----
#pragma unroll
  for (int mf = 0; mf < MR; ++mf) {
    int row = m0 + wr * (BM / WM) + mf * 16 + lg * 4;
#pragma unroll
    for (int n = 0; n < NR; ++n) {
      int col = n0 + wc * (BN / WN) + n * 16 + lr;
      float bvl = HAS_BIAS ? bias[col] : 0.f;
#pragma unroll
      for (int j = 0; j < 4; ++j) {
        float v = acc[mf][n][j] + bvl;
        if (ACT == 1) v = gelu_f(v);
        if constexpr (RES == 1) v += ((const float*)resv)[(size_t)(row + j) * N + col];
        else if constexpr (RES == 2)
          v += bfu2f(__builtin_bit_cast(unsigned short,
                                        ((const hbf*)resv)[(size_t)(row + j) * N + col]));
        if (OUT_BF16) ((hbf*)Cv)[(size_t)(row + j) * N + col] = __float2bfloat16(v);
        else ((float*)Cv)[(size_t)(row + j) * N + col] = v;
      }
    }
  }
}

// ---------------- per-head V transpose: qkv[b,s,2048+h*64+d] -> vt[(b*H+h)*64+d, s] -------
__global__ __launch_bounds__(256) void vtrans_kernel(const hbf* __restrict__ qkv,
                                                     hbf* __restrict__ vt) {
  __shared__ unsigned short tile[64][65];
  int bh = blockIdx.y, b = bh >> 4, hh = bh & 15;
  int s0 = blockIdx.x * 64;
  int d = threadIdx.x & 63, r0 = threadIdx.x >> 6;
#pragma unroll
  for (int i = 0; i < 16; ++i) {
    int r = r0 * 16 + i;
    tile[d][r] = __builtin_bit_cast(unsigned short,
                                    qkv[(size_t)(b * Ss + s0 + r) * LDQ + 2048 + hh * 64 + d]);
  }
  __syncthreads();
#pragma unroll
  for (int i = 0; i < 16; ++i) {
    int r = r0 * 16 + i;
    vt[(size_t)(bh * 64 + r) * Ss + s0 + d] = __builtin_bit_cast(hbf, tile[r][d]);
  }
}

// ---------------- causal flash attention, swapped QK^T, in-register softmax ---------------
// Grid 1024: xcd = gi&7 owns heads {bh: bh&7==xcd} (8 heads x 16 q-blocks, 4MB K/V = L2).
// Per-XCD dispatch rank kk>>3 orders blocks heavy-first ACROSS heads.
__global__ __launch_bounds__(256, 3) void attn_kernel(const hbf* __restrict__ qkv,
                                                      const hbf* __restrict__ vt,
                                                      hbf* __restrict__ ctx) {
  __shared__ __align__(16) hbf Ks[2][64 * 64];
  __shared__ __align__(16) hbf Vs[2][64 * 64];

  const int tid = threadIdx.x;
  const int wave = tid >> 6, lane = tid & 63;
  const int l31 = lane & 31, hi = lane >> 5;

  const int gi = blockIdx.x;
  const int xslot = gi & 7, kk = gi >> 3;
  const int rank = kk >> 3, hg = kk & 7;
  const int bh = hg * 8 + xslot;
  const int bx = 15 - rank;
  const int b = bh >> 4, hh = bh & 15;
  const int q0b = bx * 128;
  const int q0w = q0b + wave * 32;
  const int nsteps = (q0b + 128) >> 6;
  const int my_steps = (q0w + 95) >> 6;

  constexpr float QSCALE = 0.18033688011112042f;  // 0.125 * log2(e)
  bf16x8 qf[4];
  {
    const hbf* qrow = qkv + (size_t)(b * Ss + q0w + l31) * LDQ + hh * 64 + hi * 8;
#pragma unroll
    for (int ds = 0; ds < 4; ++ds) {
      bf16x8 t = *(const bf16x8*)(qrow + ds * 16);
#pragma unroll
      for (int e = 0; e < 8; ++e) qf[ds][e] = (__bf16)((float)t[e] * QSCALE);
    }
  }

  const hbf* kbase = qkv + 1024 + (size_t)(b * Ss) * LDQ + hh * 64;
  const hbf* vbase = vt + (size_t)(bh * 64) * Ss;
  const int i0 = tid, i1 = tid + 256;
  const int r0 = i0 >> 3, s0c = (i0 & 7), r1 = i1 >> 3, s1c = (i1 & 7);
  const int c0 = 8 * (s0c ^ (r0 & 7)), c1 = 8 * (s1c ^ (r1 & 7));

  f32x16 ot[2] = {};
  float m_run = -1e30f, l_run = 0.f;

  {
    hbf* kd = &Ks[0][0];
    hbf* vd = &Vs[0][0];
    GLDS(kbase + (size_t)r0 * LDQ + c0, kd + i0 * 8);
    GLDS(kbase + (size_t)r1 * LDQ + c1, kd + i1 * 8);
    GLDS(vbase + (size_t)r0 * Ss + c0, vd + i0 * 8);
    GLDS(vbase + (size_t)r1 * Ss + c1, vd + i1 * 8);
  }
  __syncthreads();

  int buf = 0;
  for (int it = 0; it < nsteps; ++it) {
    const int k0 = it << 6;
    if (it + 1 < nsteps) {
      hbf* kd = &Ks[buf ^ 1][0];
      hbf* vd = &Vs[buf ^ 1][0];
      GLDS(kbase + (size_t)(k0 + 64 + r0) * LDQ + c0, kd + i0 * 8);
      GLDS(kbase + (size_t)(k0 + 64 + r1) * LDQ + c1, kd + i1 * 8);
      GLDS(vbase + (size_t)r0 * Ss + k0 + 64 + c0, vd + i0 * 8);
      GLDS(vbase + (size_t)r1 * Ss + k0 + 64 + c1, vd + i1 * 8);
    }

    if (it < my_steps) {
      const hbf* kt = &Ks[buf][0];
      f32x16 st[2] = {};
      __builtin_amdgcn_s_setprio(1);
#pragma unroll
      for (int c = 0; c < 2; ++c) {
        const int krow = l31 + 32 * c;
        const int kr7 = krow & 7;
#pragma unroll
        for (int ds = 0; ds < 4; ++ds) {
          bf16x8 kf = *(const bf16x8*)(kt + krow * 64 + 8 * ((ds * 2 + hi) ^ kr7));
          st[c] = __builtin_amdgcn_mfma_f32_32x32x16_bf16(kf, qf[ds], st[c], 0, 0, 0);
        }
      }
      __builtin_amdgcn_s_setprio(0);

      if (it == my_steps - 1) {
        const int qg = q0w + l31;
#pragma unroll
        for (int c = 0; c < 2; ++c)
#pragma unroll
          for (int rg = 0; rg < 16; ++rg) {
            int kg = k0 + c * 32 + (rg & 3) + 8 * (rg >> 2) + 4 * hi;
            if (kg > qg) st[c][rg] = -3e38f;
          }
      }

      // row max: in-lane 32 + cross-half via shfl (R6-proven)
      float mx = -3e38f;
#pragma unroll
      for (int c = 0; c < 2; ++c)
#pragma unroll
        for (int rg = 0; rg < 16; ++rg) mx = fmaxf(mx, st[c][rg]);
      mx = fmaxf(mx, __shfl_xor(mx, 32));
      if (!__all(mx - m_run <= 11.541560327111707f)) {
        float mn = fmaxf(m_run, mx);
        float sc = exp2f(m_run - mn);
        m_run = mn;
        l_run *= sc;
#pragma unroll
        for (int dc = 0; dc < 2; ++dc)
#pragma unroll
          for (int rg = 0; rg < 16; ++rg) ot[dc][rg] *= sc;
      }
      float rs = 0.f;
#pragma unroll
      for (int c = 0; c < 2; ++c)
#pragma unroll
        for (int rg = 0; rg < 16; ++rg) {
          float p = exp2f(st[c][rg] - m_run);
          st[c][rg] = p;
          rs += p;
        }
      rs += __shfl_xor(rs, 32);
      l_run += rs;

      // P repack (R6-proven shfl+select form)
      bf16x8 pf[2][2];
#pragma unroll
      for (int c = 0; c < 2; ++c)
#pragma unroll
        for (int ks = 0; ks < 2; ++ks) {
          const int rb = ks * 8;
          u32 a0 = pkbf(st[c][rb + 0], st[c][rb + 1]);
          u32 a1 = pkbf(st[c][rb + 2], st[c][rb + 3]);
          u32 b0 = pkbf(st[c][rb + 4], st[c][rb + 5]);
          u32 b1 = pkbf(st[c][rb + 6], st[c][rb + 7]);
          u32 pa0 = __shfl_xor(a0, 32), pa1 = __shfl_xor(a1, 32);
          u32 pb0 = __shfl_xor(b0, 32), pb1 = __shfl_xor(b1, 32);
          u32x4 f;
          f.x = hi ? pb0 : a0;
          f.y = hi ? pb1 : a1;
          f.z = hi ? b0 : pa0;
          f.w = hi ? b1 : pa1;
          pf[c][ks] = __builtin_bit_cast(bf16x8, f);
        }

      const hbf* vtl = &Vs[buf][0];
      __builtin_amdgcn_s_setprio(1);
#pragma unroll
      for (int dc = 0; dc < 2; ++dc) {
        const int vrow = l31 + 32 * dc;
        const int vr7 = vrow & 7;
#pragma unroll
        for (int c = 0; c < 2; ++c)
#pragma unroll
          for (int ks = 0; ks < 2; ++ks) {
            bf16x8 vf = *(const bf16x8*)(vtl + vrow * 64 + 8 * ((c * 4 + ks * 2 + hi) ^ vr7));
            ot[dc] = __builtin_amdgcn_mfma_f32_32x32x16_bf16(vf, pf[c][ks], ot[dc], 0, 0, 0);
          }
      }
      __builtin_amdgcn_s_setprio(0);
    }

    __syncthreads();
    buf ^= 1;
  }

  const float inv = __builtin_amdgcn_rcpf(l_run);
  hbf* crow = ctx + (size_t)(b * Ss + q0w + l31) * Dm + hh * 64;
#pragma unroll
  for (int dc = 0; dc < 2; ++dc)
#pragma unroll
    for (int rg = 0; rg < 4; ++rg) {
      ushort4 w;
      w.x = f2bfu(ot[dc][rg * 4 + 0] * inv);
      w.y = f2bfu(ot[dc][rg * 4 + 1] * inv);
      w.z = f2bfu(ot[dc][rg * 4 + 2] * inv);
      w.w = f2bfu(ot[dc][rg * 4 + 3] * inv);
      *(ushort4*)(crow + dc * 32 + rg * 8 + hi * 4) = w;
    }
}

// -----------------------------------------------------------------------------------------
extern "C" void kernel_launch(void* const* d_in, const int* in_sizes, int n_in,
                              void* d_out, int out_size, void* d_ws, size_t ws_size,
                              hipStream_t stream) {
  const float* x  = (const float*)d_in[0];
  const float* Wq = (const float*)d_in[1];
  const float* Wk = (const float*)d_in[2];
  const float* Wv = (const float*)d_in[3];
  const float* Wo = (const float*)d_in[4];
  const float* bo = (const float*)d_in[5];
  const float* W1 = (const float*)d_in[6];
  const float* b1 = (const float*)d_in[7];
  const float* W2 = (const float*)d_in[8];
  const float* b2 = (const float*)d_in[9];
  const float* g1 = (const float*)d_in[10];
  const float* s1 = (const float*)d_in[11];
  const float* g2 = (const float*)d_in[12];
  const float* s2 = (const float*)d_in[13];
  float* out = (float*)d_out;

  char* ws = (char*)d_ws;
  constexpr size_t MB = 1024ull * 1024ull;
  hbf* wqkvT = (hbf*)(ws + 0 * MB);    // 6MB [3072][1024]
  hbf* woT   = (hbf*)(ws + 6 * MB);    // 2MB
  hbf* w1T   = (hbf*)(ws + 8 * MB);    // 8MB
  hbf* w2T   = (hbf*)(ws + 16 * MB);   // 8MB
  hbf* xln   = (hbf*)(ws + 24 * MB);   // 16MB (reused: ctx, then y2)
  hbf* ctx   = (hbf*)(ws + 24 * MB);
  hbf* y2    = (hbf*)(ws + 24 * MB);
  hbf* qkvb  = (hbf*)(ws + 40 * MB);   // 48MB [8192][3072]
  hbf* vtb   = (hbf*)(ws + 88 * MB);   // 16MB
  hbf* ff1   = (hbf*)(ws + 40 * MB);   // 64MB (over dead qkv/vt)
  hbf* hbb   = (hbf*)(ws + 104 * MB);  // 16MB bf16 residual trunk
  (void)ws_size; (void)in_sizes; (void)n_in; (void)out_size;

  const int BS = Bb * Ss;  // 8192 rows

  // 1) all weights -> bf16 transposed [N,K] (one launch)
  wtransall_kernel<<<12288, 256, 0, stream>>>(Wq, Wk, Wv, Wo, W1, W2,
                                              wqkvT, woT, w1T, w2T);

  // 2) LN1
  ln_kernel<false><<<BS, 256, 0, stream>>>(x, g1, s1, xln);

  // 3) fused QKV projection: [8192,1024] @ [1024,3072]  (grid 64x24=1536, 2 blk/CU)
  gemm8<128, 128, 2, 2, 256, 2, 0, false, 0, true><<<1536, 256, 0, stream>>>(
      xln, wqkvT, qkvb, nullptr, nullptr, BS, LDQ, Dm);

  // 4) V transpose per head
  vtrans_kernel<<<dim3(Ss / 64, Bb * Hh), 256, 0, stream>>>(qkvb, vtb);

  // 5) flash attention
  attn_kernel<<<dim3(1024), 256, 0, stream>>>(qkvb, vtb, ctx);

  // 6) output projection + bias + residual(x fp32) -> h (bf16)  (grid 512)
  gemm8<128, 128, 2, 2, 256, 2, 0, true, 1, true><<<512, 256, 0, stream>>>(
      ctx, woT, hbb, bo, x, BS, Dm, Dm);

  // 7) LN2 (bf16 in)
  ln_kernel<true><<<BS, 256, 0, stream>>>(hbb, g2, s2, y2);

  // 8) FF1 + bias + GELU  (grid 64x32=2048)
  gemm8<128, 128, 2, 2, 256, 2, 1, true, 0, true><<<2048, 256, 0, stream>>>(
      y2, w1T, ff1, b1, nullptr, BS, DFm, Dm);

  // 9) FF2 + bias + residual(h bf16) -> out (fp32)  (grid 512, K=4096)
  gemm8<128, 128, 2, 2, 256, 2, 0, true, 2, false><<<512, 256, 0, stream>>>(
      ff1, w2T, out, b2, hbb, BS, Dm, DFm);
}

// Round 16
// 335.148 us; speedup vs baseline: 1.1322x; 1.0260x over previous
//
#include <hip/hip_runtime.h>
#include <hip/hip_bf16.h>

#define DEV __device__ __forceinline__

typedef __bf16 bf16x8 __attribute__((ext_vector_type(8)));
typedef __bf16 bf16x2v __attribute__((ext_vector_type(2)));
typedef float f32x4 __attribute__((ext_vector_type(4)));
typedef float f32x16 __attribute__((ext_vector_type(16)));
typedef unsigned int u32;
typedef unsigned int u32x4 __attribute__((ext_vector_type(4)));
typedef __hip_bfloat16 hbf;

constexpr int Dm = 1024;
constexpr int Hh = 16;
constexpr int Ss = 2048;
constexpr int Bb = 4;
constexpr int DFm = 4096;
constexpr int LDQ = 3072;  // fused qkv row stride

DEV unsigned short f2bfu(float f) {
  hbf h = __float2bfloat16(f);
  return __builtin_bit_cast(unsigned short, h);
}

DEV float bfu2f(unsigned short u) { return __builtin_bit_cast(float, (u32)u << 16); }

DEV u32 pkbf(float x, float y) {
  bf16x2v v = {(__bf16)x, (__bf16)y};
  return __builtin_bit_cast(u32, v);
}

DEV float gelu_f(float x) {
  float e = __expf(-1.5957691216057308f * (x + 0.044715f * x * x * x));
  return x * __builtin_amdgcn_rcpf(1.f + e);
}

template <int N>
DEV void s_vmcnt() {
  if constexpr (N == 0) asm volatile("s_waitcnt vmcnt(0)" ::: "memory");
  else if constexpr (N == 5) asm volatile("s_waitcnt vmcnt(5)" ::: "memory");
  else if constexpr (N == 6) asm volatile("s_waitcnt vmcnt(6)" ::: "memory");
  else if constexpr (N == 8) asm volatile("s_waitcnt vmcnt(8)" ::: "memory");
  else static_assert(N == 0, "unsupported vmcnt");
}

#define GLDS(src, dst)                                                                     \
  __builtin_amdgcn_global_load_lds((const __attribute__((address_space(1))) void*)(src),   \
                                   (__attribute__((address_space(3))) void*)(dst), 16, 0, 0)

// ========== fused prep: 6 weight transposes (blocks 0..12287) + LN1 (blocks 12288..20479) =
// Independent ops merged into one launch so the BW-bound transpose overlaps LN1 instead of
// serializing on the stream.
__global__ __launch_bounds__(256) void prep_kernel(
    const float* __restrict__ Wq, const float* __restrict__ Wk,
    const float* __restrict__ Wv, const float* __restrict__ Wo,
    const float* __restrict__ W1, const float* __restrict__ W2,
    hbf* __restrict__ dqkv, hbf* __restrict__ dwo,
    hbf* __restrict__ dw1, hbf* __restrict__ dw2,
    const float* __restrict__ x, const float* __restrict__ g1,
    const float* __restrict__ s1, hbf* __restrict__ xln) {
  const int i = blockIdx.x;
  if (i < 12288) {
    __shared__ float tile[32][33];
    const float* W;
    hbf* Wt;
    int K, N, k0, n0;
    if (i < 4096) {
      int z = i >> 10, j = i & 1023;
      W = z == 0 ? Wq : z == 1 ? Wk : z == 2 ? Wv : Wo;
      Wt = z == 3 ? dwo : dqkv + (size_t)z * 1024 * 1024;
      K = 1024; N = 1024; k0 = (j & 31) * 32; n0 = (j >> 5) * 32;
    } else if (i < 8192) {
      int j = i - 4096;
      W = W1; Wt = dw1; K = 1024; N = 4096;
      k0 = (j & 31) * 32; n0 = (j >> 5) * 32;
    } else {
      int j = i - 8192;
      W = W2; Wt = dw2; K = 4096; N = 1024;
      k0 = (j & 127) * 32; n0 = (j >> 7) * 32;
    }
    int tx = threadIdx.x & 31, ty = threadIdx.x >> 5;
    for (int r = ty; r < 32; r += 8) tile[r][tx] = W[(size_t)(k0 + r) * N + n0 + tx];
    __syncthreads();
    for (int r = ty; r < 32; r += 8)
      Wt[(size_t)(n0 + r) * K + k0 + tx] = __float2bfloat16(tile[tx][r]);
  } else {
    const int bid = i - 12288;
    int row = ((bid & 7) << 10) | (bid >> 3);  // row->XCD remap
    int t = threadIdx.x;
    float4 v = ((const float4*)(x + (size_t)row * Dm))[t];
    float s = v.x + v.y + v.z + v.w;
    float q = v.x * v.x + v.y * v.y + v.z * v.z + v.w * v.w;
#pragma unroll
    for (int off = 32; off > 0; off >>= 1) {
      s += __shfl_down(s, off);
      q += __shfl_down(q, off);
    }
    __shared__ float red[10];
    int wave = t >> 6, lane = t & 63;
    if (lane == 0) { red[wave] = s; red[4 + wave] = q; }
    __syncthreads();
    if (t == 0) {
      float ts = red[0] + red[1] + red[2] + red[3];
      float tq = red[4] + red[5] + red[6] + red[7];
      float mean = ts * (1.f / Dm);
      float var = tq * (1.f / Dm) - mean * mean;
      red[8] = mean;
      red[9] = rsqrtf(var + 1e-5f);
    }
    __syncthreads();
    float mean = red[8], inv = red[9];
    float4 gv = ((const float4*)g1)[t];
    float4 bv = ((const float4*)s1)[t];
    ushort4 o;
    o.x = f2bfu(gv.x * (v.x - mean) * inv + bv.x);
    o.y = f2bfu(gv.y * (v.y - mean) * inv + bv.y);
    o.z = f2bfu(gv.z * (v.z - mean) * inv + bv.z);
    o.w = f2bfu(gv.w * (v.w - mean) * inv + bv.w);
    ((ushort4*)(xln + (size_t)row * Dm))[t] = o;
  }
}

// ---------------- layernorm (bf16 in, bf16 out), one block per row, row->XCD remap --------
__global__ __launch_bounds__(256) void ln_kernel(const hbf* __restrict__ xv,
                                                 const float* __restrict__ g,
                                                 const float* __restrict__ b,
                                                 hbf* __restrict__ y) {
  int row = ((blockIdx.x & 7) << 10) | (blockIdx.x >> 3);
  int t = threadIdx.x;
  float4 v;
  ushort4 u = ((const ushort4*)(xv + (size_t)row * Dm))[t];
  v.x = bfu2f(u.x); v.y = bfu2f(u.y); v.z = bfu2f(u.z); v.w = bfu2f(u.w);
  float s = v.x + v.y + v.z + v.w;
  float q = v.x * v.x + v.y * v.y + v.z * v.z + v.w * v.w;
#pragma unroll
  for (int off = 32; off > 0; off >>= 1) {
    s += __shfl_down(s, off);
    q += __shfl_down(q, off);
  }
  __shared__ float red[10];
  int wave = t >> 6, lane = t & 63;
  if (lane == 0) { red[wave] = s; red[4 + wave] = q; }
  __syncthreads();
  if (t == 0) {
    float ts = red[0] + red[1] + red[2] + red[3];
    float tq = red[4] + red[5] + red[6] + red[7];
    float mean = ts * (1.f / Dm);
    float var = tq * (1.f / Dm) - mean * mean;
    red[8] = mean;
    red[9] = rsqrtf(var + 1e-5f);
  }
  __syncthreads();
  float mean = red[8], inv = red[9];
  float4 gv = ((const float4*)g)[t];
  float4 bv = ((const float4*)b)[t];
  ushort4 o;
  o.x = f2bfu(gv.x * (v.x - mean) * inv + bv.x);
  o.y = f2bfu(gv.y * (v.y - mean) * inv + bv.y);
  o.z = f2bfu(gv.z * (v.z - mean) * inv + bv.z);
  o.w = f2bfu(gv.w * (v.w - mean) * inv + bv.w);
  ((ushort4*)(y + (size_t)row * Dm))[t] = o;
}

// ================= tiled GEMM, 2-phase schedule, 2 blocks/CU, L2-supertiled ===============
// See R13/R15 comments. VTR: for the QKV GEMM, n-panels with col>=2048 (the V block) are
// written DIRECTLY TRANSPOSED to vtrout[(b*1024 + col-2048)*Ss + s] (8B s-contiguous chunks)
// instead of qkvb — fuses the old vtrans kernel (V-range of qkvb had no other consumer).
// RES: 0 none, 1 fp32, 2 bf16.
template <int BM, int BN, int WM, int WN, int NTHR, int NPH, int ACT, bool HAS_BIAS, int RES,
          bool OUT_BF16, int VTR>
__global__ __launch_bounds__(NTHR, 2) void gemm8(const hbf* __restrict__ A,
                                                 const hbf* __restrict__ Bt,
                                                 void* __restrict__ Cv,
                                                 const float* __restrict__ bias,
                                                 const void* __restrict__ resv,
                                                 hbf* __restrict__ vtrout,
                                                 int M, int N, int K) {
  constexpr int MR = (BM / WM) / 16, NR = (BN / WN) / 16;
  constexpr int MQ = MR / 2, NQ = NR / 2;
  constexpr int RPA = (BM / WM) / 2;
  constexpr int RPB = (BN / WN) / 2;
  constexpr int ASL = (BM / 2) * 64;
  constexpr int BSL = (BN / 2) * 64;
  constexpr int PERBUF = 2 * ASL + 2 * BSL;
  constexpr int ALD = ASL / (8 * NTHR);
  constexpr int BLD = BSL / (8 * NTHR);
  constexpr int VPB = 2 * ALD + BLD;
  constexpr int VP4 = 2 * ALD + 2 * BLD;

  __shared__ __align__(16) hbf lds[2 * PERBUF];

  const int tid = threadIdx.x;
  const int lane = tid & 63, wave = tid >> 6;
  const int wr = wave / WN, wc = wave % WN;
  const int lr = lane & 15, lg = lane >> 4;

  const int xcd = blockIdx.x & 7, oidx = blockIdx.x >> 3;
  const int gsup = oidx >> 6, r6 = oidx & 63;
  const int m0 = (xcd * 8 + (r6 >> 3)) * BM;
  const int n0 = (gsup * 8 + (r6 & 7)) * BN;

  const hbf* Ab = A + (size_t)m0 * K;
  const hbf* Bb = Bt + (size_t)n0 * K;

  f32x4 acc[MR][NR] = {};

  auto stageA = [&](int mh, int t, int p) {
#pragma unroll
    for (int l = 0; l < ALD; ++l) {
      int ci = l * NTHR + tid;
      int r = ci >> 3, c = ci & 7;
      int piece = r / RPA, rl = r % RPA;
      int grow = piece * (BM / WM) + mh * RPA + rl;
      int gk = t * 64 + ((c ^ (r & 7)) << 3);
      GLDS(Ab + (size_t)grow * K + gk, lds + p * PERBUF + mh * ASL + (size_t)ci * 8);
    }
  };
  auto stageB = [&](int nh, int t, int p) {
#pragma unroll
    for (int l = 0; l < BLD; ++l) {
      int ci = l * NTHR + tid;
      int r = ci >> 3, c = ci & 7;
      int piece = r / RPB, rl = r % RPB;
      int grow = piece * (BN / WN) + nh * RPB + rl;
      int gk = t * 64 + ((c ^ (r & 7)) << 3);
      GLDS(Bb + (size_t)grow * K + gk, lds + p * PERBUF + 2 * ASL + nh * BSL + (size_t)ci * 8);
    }
  };
  auto ldAfull = [&](bf16x8 (&af)[MR][2], int p) {
#pragma unroll
    for (int f = 0; f < MR; ++f)
#pragma unroll
      for (int ks = 0; ks < 2; ++ks) {
        int mh = f >> 1, i = f & 1;
        const hbf* base = lds + p * PERBUF + mh * ASL;
        int row = wr * RPA + i * 16 + lr;
        int slot = (ks * 4 + lg) ^ (lr & 7);
        af[f][ks] = *(const bf16x8*)(base + (size_t)row * 64 + slot * 8);
      }
  };
  auto ldA = [&](bf16x8 (&af)[MQ][2], int mh, int p) {
    const hbf* base = lds + p * PERBUF + mh * ASL;
#pragma unroll
    for (int i = 0; i < MQ; ++i)
#pragma unroll
      for (int ks = 0; ks < 2; ++ks) {
        int row = wr * RPA + i * 16 + lr;
        int slot = (ks * 4 + lg) ^ (lr & 7);
        af[i][ks] = *(const bf16x8*)(base + (size_t)row * 64 + slot * 8);
      }
  };
  auto ldB = [&](bf16x8 (&bf)[NQ][2], int nh, int p) {
    const hbf* base = lds + p * PERBUF + 2 * ASL + nh * BSL;
#pragma unroll
    for (int j = 0; j < NQ; ++j)
#pragma unroll
      for (int ks = 0; ks < 2; ++ks) {
        int row = wc * RPB + j * 16 + lr;
        int slot = (ks * 4 + lg) ^ (lr & 7);
        bf[j][ks] = *(const bf16x8*)(base + (size_t)row * 64 + slot * 8);
      }
  };

#define SYNC_LGKM()                                        \
  do {                                                     \
    __builtin_amdgcn_s_barrier();                          \
    asm volatile("s_waitcnt lgkmcnt(0)" ::: "memory");     \
    __builtin_amdgcn_sched_barrier(0);                     \
  } while (0)

#define MFMA_Q(av, bv, mh, nh)                                                        \
  do {                                                                                \
    __builtin_amdgcn_s_setprio(1);                                                    \
    _Pragma("unroll") for (int i_ = 0; i_ < MQ; ++i_)                                 \
    _Pragma("unroll") for (int j_ = 0; j_ < NQ; ++j_)                                 \
    _Pragma("unroll") for (int k_ = 0; k_ < 2; ++k_)                                  \
      acc[(mh) * MQ + i_][(nh) * NQ + j_] = __builtin_amdgcn_mfma_f32_16x16x32_bf16(  \
          (av)[i_][k_], (bv)[j_][k_], acc[(mh) * MQ + i_][(nh) * NQ + j_], 0, 0, 0);  \
    __builtin_amdgcn_s_setprio(0);                                                    \
  } while (0)

#define MFMA_H(av, bv, nh)                                                            \
  do {                                                                                \
    __builtin_amdgcn_s_setprio(1);                                                    \
    _Pragma("unroll") for (int f_ = 0; f_ < MR; ++f_)                                 \
    _Pragma("unroll") for (int j_ = 0; j_ < NQ; ++j_)                                 \
    _Pragma("unroll") for (int k_ = 0; k_ < 2; ++k_)                                  \
      acc[f_][(nh) * NQ + j_] = __builtin_amdgcn_mfma_f32_16x16x32_bf16(              \
          (av)[f_][k_], (bv)[j_][k_], acc[f_][(nh) * NQ + j_], 0, 0, 0);              \
    __builtin_amdgcn_s_setprio(0);                                                    \
  } while (0)

  const int T = K >> 6;

  if constexpr (NPH == 4) {
    stageA(0, 0, 0); stageB(0, 0, 0); stageA(1, 0, 0); stageB(1, 0, 0);
    stageA(0, 1, 1); stageB(0, 1, 1); stageA(1, 1, 1); stageB(1, 1, 1);
    s_vmcnt<VP4>();
    __builtin_amdgcn_s_barrier();

    for (int t = 0; t < T; ++t) {
      const int p = t & 1;
      bf16x8 a0[MQ][2], a1[MQ][2], b0[NQ][2], b1[NQ][2];
      ldA(a0, 0, p);
      ldB(b0, 0, p);
      asm volatile("s_waitcnt lgkmcnt(8)" ::: "memory");
      SYNC_LGKM();
      MFMA_Q(a0, b0, 0, 0);
      __builtin_amdgcn_s_barrier();
      ldA(a1, 1, p);
      if (t + 2 < T) { stageA(0, t + 2, p); stageB(0, t + 2, p); }
      SYNC_LGKM();
      MFMA_Q(a1, b0, 1, 0);
      __builtin_amdgcn_s_barrier();
      ldB(b1, 1, p);
      if (t + 2 < T) stageA(1, t + 2, p);
      SYNC_LGKM();
      MFMA_Q(a1, b1, 1, 1);
      __builtin_amdgcn_s_barrier();
      if (t + 2 < T) stageB(1, t + 2, p);
      MFMA_Q(a0, b1, 0, 1);
      if (t + 1 < T) {
        if (t + 2 < T) s_vmcnt<VP4>();
        else s_vmcnt<0>();
      }
      __builtin_amdgcn_s_barrier();
    }
  } else {
    stageA(0, 0, 0); stageA(1, 0, 0); stageB(0, 0, 0); stageB(1, 0, 0);
    stageA(0, 1, 1); stageA(1, 1, 1); stageB(0, 1, 1);
    s_vmcnt<VPB>();
    __builtin_amdgcn_s_barrier();

    for (int t = 0; t < T; ++t) {
      const int p = t & 1;
      bf16x8 af[MR][2], b0[NQ][2], b1[NQ][2];
      ldAfull(af, p);
      ldB(b0, 0, p);
      if (t + 1 < T) stageB(1, t + 1, p ^ 1);
      asm volatile("s_waitcnt lgkmcnt(8)" ::: "memory");
      SYNC_LGKM();
      MFMA_H(af, b0, 0);
      __builtin_amdgcn_s_barrier();
      ldB(b1, 1, p);
      if (t + 2 < T) { stageA(0, t + 2, p); stageA(1, t + 2, p); stageB(0, t + 2, p); }
      SYNC_LGKM();
      MFMA_H(af, b1, 1);
      if (t + 1 < T) {
        if (t + 2 < T) s_vmcnt<VPB>();
        else s_vmcnt<0>();
      }
      __builtin_amdgcn_s_barrier();
    }
  }
#undef SYNC_LGKM
#undef MFMA_Q
#undef MFMA_H

  // ---- epilogue ----
#pragma unroll
  for (int mf = 0; mf < MR; ++mf) {
    int row = m0 + wr * (BM / WM) + mf * 16 + lg * 4;
#pragma unroll
    for (int n = 0; n < NR; ++n) {
      int col = n0 + wc * (BN / WN) + n * 16 + lr;
      float bvl = HAS_BIAS ? bias[col] : 0.f;
      float tv[4];
#pragma unroll
      for (int j = 0; j < 4; ++j) {
        float v = acc[mf][n][j] + bvl;
        if (ACT == 1) v = gelu_f(v);
        if constexpr (RES == 1) v += ((const float*)resv)[(size_t)(row + j) * N + col];
        else if constexpr (RES == 2)
          v += bfu2f(__builtin_bit_cast(unsigned short,
                                        ((const hbf*)resv)[(size_t)(row + j) * N + col]));
        tv[j] = v;
      }
      if constexpr (VTR != 0) {
        if (col >= 2048) {
          // transposed V write: vtrout[(b*1024 + col-2048)][s..s+3]
          ushort4 w;
          w.x = f2bfu(tv[0]); w.y = f2bfu(tv[1]); w.z = f2bfu(tv[2]); w.w = f2bfu(tv[3]);
          int bb = row >> 11;
          size_t vrow = (size_t)(bb * 1024 + col - 2048);
          *(ushort4*)((unsigned short*)vtrout + vrow * Ss + (row & 2047)) = w;
          continue;
        }
      }
#pragma unroll
      for (int j = 0; j < 4; ++j) {
        if (OUT_BF16) ((hbf*)Cv)[(size_t)(row + j) * N + col] = __float2bfloat16(tv[j]);
        else ((float*)Cv)[(size_t)(row + j) * N + col] = tv[j];
      }
    }
  }
}

// ---------------- causal flash attention, swapped QK^T, in-register softmax ---------------
// Grid 1024 = 4 blocks/CU (all co-resident; every critical-path q-block starts at t=0).
// xcd = gi&7 owns heads {bh: bh&7==xcd} (8 heads x 16 q-blocks, 4MB K/V = L2); per-XCD
// dispatch rank orders blocks heavy-first ACROSS heads.
__global__ __launch_bounds__(256, 4) void attn_kernel(const hbf* __restrict__ qkv,
                                                      const hbf* __restrict__ vt,
                                                      hbf* __restrict__ ctx) {
  __shared__ __align__(16) hbf Ks[2][64 * 64];
  __shared__ __align__(16) hbf Vs[2][64 * 64];

  const int tid = threadIdx.x;
  const int wave = tid >> 6, lane = tid & 63;
  const int l31 = lane & 31, hi = lane >> 5;

  const int gi = blockIdx.x;
  const int xslot = gi & 7, kk = gi >> 3;
  const int rank = kk >> 3, hg = kk & 7;
  const int bh = hg * 8 + xslot;
  const int bx = 15 - rank;
  const int b = bh >> 4, hh = bh & 15;
  const int q0b = bx * 128;
  const int q0w = q0b + wave * 32;
  const int nsteps = (q0b + 128) >> 6;
  const int my_steps = (q0w + 95) >> 6;

  constexpr float QSCALE = 0.18033688011112042f;  // 0.125 * log2(e)
  bf16x8 qf[4];
  {
    const hbf* qrow = qkv + (size_t)(b * Ss + q0w + l31) * LDQ + hh * 64 + hi * 8;
#pragma unroll
    for (int ds = 0; ds < 4; ++ds) {
      bf16x8 t = *(const bf16x8*)(qrow + ds * 16);
#pragma unroll
      for (int e = 0; e < 8; ++e) qf[ds][e] = (__bf16)((float)t[e] * QSCALE);
    }
  }

  const hbf* kbase = qkv + 1024 + (size_t)(b * Ss) * LDQ + hh * 64;
  const hbf* vbase = vt + (size_t)(bh * 64) * Ss;
  const int i0 = tid, i1 = tid + 256;
  const int r0 = i0 >> 3, s0c = (i0 & 7), r1 = i1 >> 3, s1c = (i1 & 7);
  const int c0 = 8 * (s0c ^ (r0 & 7)), c1 = 8 * (s1c ^ (r1 & 7));

  f32x16 ot[2] = {};
  float m_run = -1e30f, l_run = 0.f;

  {
    hbf* kd = &Ks[0][0];
    hbf* vd = &Vs[0][0];
    GLDS(kbase + (size_t)r0 * LDQ + c0, kd + i0 * 8);
    GLDS(kbase + (size_t)r1 * LDQ + c1, kd + i1 * 8);
    GLDS(vbase + (size_t)r0 * Ss + c0, vd + i0 * 8);
    GLDS(vbase + (size_t)r1 * Ss + c1, vd + i1 * 8);
  }
  __syncthreads();

  int buf = 0;
  for (int it = 0; it < nsteps; ++it) {
    const int k0 = it << 6;
    if (it + 1 < nsteps) {
      hbf* kd = &Ks[buf ^ 1][0];
      hbf* vd = &Vs[buf ^ 1][0];
      GLDS(kbase + (size_t)(k0 + 64 + r0) * LDQ + c0, kd + i0 * 8);
      GLDS(kbase + (size_t)(k0 + 64 + r1) * LDQ + c1, kd + i1 * 8);
      GLDS(vbase + (size_t)r0 * Ss + k0 + 64 + c0, vd + i0 * 8);
      GLDS(vbase + (size_t)r1 * Ss + k0 + 64 + c1, vd + i1 * 8);
    }

    if (it < my_steps) {
      const hbf* kt = &Ks[buf][0];
      f32x16 st[2] = {};
      __builtin_amdgcn_s_setprio(1);
#pragma unroll
      for (int c = 0; c < 2; ++c) {
        const int krow = l31 + 32 * c;
        const int kr7 = krow & 7;
#pragma unroll
        for (int ds = 0; ds < 4; ++ds) {
          bf16x8 kf = *(const bf16x8*)(kt + krow * 64 + 8 * ((ds * 2 + hi) ^ kr7));
          st[c] = __builtin_amdgcn_mfma_f32_32x32x16_bf16(kf, qf[ds], st[c], 0, 0, 0);
        }
      }
      __builtin_amdgcn_s_setprio(0);

      if (it == my_steps - 1) {
        const int qg = q0w + l31;
#pragma unroll
        for (int c = 0; c < 2; ++c)
#pragma unroll
          for (int rg = 0; rg < 16; ++rg) {
            int kg = k0 + c * 32 + (rg & 3) + 8 * (rg >> 2) + 4 * hi;
            if (kg > qg) st[c][rg] = -3e38f;
          }
      }

      float mx = -3e38f;
#pragma unroll
      for (int c = 0; c < 2; ++c)
#pragma unroll
        for (int rg = 0; rg < 16; ++rg) mx = fmaxf(mx, st[c][rg]);
      mx = fmaxf(mx, __shfl_xor(mx, 32));
      if (!__all(mx - m_run <= 11.541560327111707f)) {
        float mn = fmaxf(m_run, mx);
        float sc = exp2f(m_run - mn);
        m_run = mn;
        l_run *= sc;
#pragma unroll
        for (int dc = 0; dc < 2; ++dc)
#pragma unroll
          for (int rg = 0; rg < 16; ++rg) ot[dc][rg] *= sc;
      }
      float rs = 0.f;
#pragma unroll
      for (int c = 0; c < 2; ++c)
#pragma unroll
        for (int rg = 0; rg < 16; ++rg) {
          float p = exp2f(st[c][rg] - m_run);
          st[c][rg] = p;
          rs += p;
        }
      rs += __shfl_xor(rs, 32);
      l_run += rs;

      bf16x8 pf[2][2];
#pragma unroll
      for (int c = 0; c < 2; ++c)
#pragma unroll
        for (int ks = 0; ks < 2; ++ks) {
          const int rb = ks * 8;
          u32 a0 = pkbf(st[c][rb + 0], st[c][rb + 1]);
          u32 a1 = pkbf(st[c][rb + 2], st[c][rb + 3]);
          u32 b0 = pkbf(st[c][rb + 4], st[c][rb + 5]);
          u32 b1 = pkbf(st[c][rb + 6], st[c][rb + 7]);
          u32 pa0 = __shfl_xor(a0, 32), pa1 = __shfl_xor(a1, 32);
          u32 pb0 = __shfl_xor(b0, 32), pb1 = __shfl_xor(b1, 32);
          u32x4 f;
          f.x = hi ? pb0 : a0;
          f.y = hi ? pb1 : a1;
          f.z = hi ? b0 : pa0;
          f.w = hi ? b1 : pa1;
          pf[c][ks] = __builtin_bit_cast(bf16x8, f);
        }

      const hbf* vtl = &Vs[buf][0];
      __builtin_amdgcn_s_setprio(1);
#pragma unroll
      for (int dc = 0; dc < 2; ++dc) {
        const int vrow = l31 + 32 * dc;
        const int vr7 = vrow & 7;
#pragma unroll
        for (int c = 0; c < 2; ++c)
#pragma unroll
          for (int ks = 0; ks < 2; ++ks) {
            bf16x8 vf = *(const bf16x8*)(vtl + vrow * 64 + 8 * ((c * 4 + ks * 2 + hi) ^ vr7));
            ot[dc] = __builtin_amdgcn_mfma_f32_32x32x16_bf16(vf, pf[c][ks], ot[dc], 0, 0, 0);
          }
      }
      __builtin_amdgcn_s_setprio(0);
    }

    __syncthreads();
    buf ^= 1;
  }

  const float inv = __builtin_amdgcn_rcpf(l_run);
  hbf* crow = ctx + (size_t)(b * Ss + q0w + l31) * Dm + hh * 64;
#pragma unroll
  for (int dc = 0; dc < 2; ++dc)
#pragma unroll
    for (int rg = 0; rg < 4; ++rg) {
      ushort4 w;
      w.x = f2bfu(ot[dc][rg * 4 + 0] * inv);
      w.y = f2bfu(ot[dc][rg * 4 + 1] * inv);
      w.z = f2bfu(ot[dc][rg * 4 + 2] * inv);
      w.w = f2bfu(ot[dc][rg * 4 + 3] * inv);
      *(ushort4*)(crow + dc * 32 + rg * 8 + hi * 4) = w;
    }
}

// -----------------------------------------------------------------------------------------
extern "C" void kernel_launch(void* const* d_in, const int* in_sizes, int n_in,
                              void* d_out, int out_size, void* d_ws, size_t ws_size,
                              hipStream_t stream) {
  const float* x  = (const float*)d_in[0];
  const float* Wq = (const float*)d_in[1];
  const float* Wk = (const float*)d_in[2];
  const float* Wv = (const float*)d_in[3];
  const float* Wo = (const float*)d_in[4];
  const float* bo = (const float*)d_in[5];
  const float* W1 = (const float*)d_in[6];
  const float* b1 = (const float*)d_in[7];
  const float* W2 = (const float*)d_in[8];
  const float* b2 = (const float*)d_in[9];
  const float* g1 = (const float*)d_in[10];
  const float* s1 = (const float*)d_in[11];
  const float* g2 = (const float*)d_in[12];
  const float* s2 = (const float*)d_in[13];
  float* out = (float*)d_out;

  char* ws = (char*)d_ws;
  constexpr size_t MB = 1024ull * 1024ull;
  hbf* wqkvT = (hbf*)(ws + 0 * MB);    // 6MB [3072][1024]
  hbf* woT   = (hbf*)(ws + 6 * MB);    // 2MB
  hbf* w1T   = (hbf*)(ws + 8 * MB);    // 8MB
  hbf* w2T   = (hbf*)(ws + 16 * MB);   // 8MB
  hbf* xln   = (hbf*)(ws + 24 * MB);   // 16MB (reused: ctx, then y2)
  hbf* ctx   = (hbf*)(ws + 24 * MB);
  hbf* y2    = (hbf*)(ws + 24 * MB);
  hbf* qkvb  = (hbf*)(ws + 40 * MB);   // 48MB [8192][3072] (V range unused)
  hbf* vtb   = (hbf*)(ws + 88 * MB);   // 16MB
  hbf* ff1   = (hbf*)(ws + 40 * MB);   // 64MB (over dead qkv/vt)
  hbf* hbb   = (hbf*)(ws + 104 * MB);  // 16MB bf16 residual trunk
  (void)ws_size; (void)in_sizes; (void)n_in; (void)out_size;

  const int BS = Bb * Ss;  // 8192 rows

  // 1) weights->bf16 transposed + LN1, one fused launch
  prep_kernel<<<20480, 256, 0, stream>>>(Wq, Wk, Wv, Wo, W1, W2,
                                         wqkvT, woT, w1T, w2T, x, g1, s1, xln);

  // 2) fused QKV projection; V panels written transposed to vtb (vtrans fused)
  gemm8<128, 128, 2, 2, 256, 2, 0, false, 0, true, 1><<<1536, 256, 0, stream>>>(
      xln, wqkvT, qkvb, nullptr, nullptr, vtb, BS, LDQ, Dm);

  // 3) flash attention (4 blocks/CU, fully co-resident)
  attn_kernel<<<dim3(1024), 256, 0, stream>>>(qkvb, vtb, ctx);

  // 4) output projection + bias + residual(x fp32) -> h (bf16)
  gemm8<128, 128, 2, 2, 256, 2, 0, true, 1, true, 0><<<512, 256, 0, stream>>>(
      ctx, woT, hbb, bo, x, nullptr, BS, Dm, Dm);

  // 5) LN2 (bf16 in)
  ln_kernel<<<BS, 256, 0, stream>>>(hbb, g2, s2, y2);

  // 6) FF1 + bias + GELU
  gemm8<128, 128, 2, 2, 256, 2, 1, true, 0, true, 0><<<2048, 256, 0, stream>>>(
      y2, w1T, ff1, b1, nullptr, nullptr, BS, DFm, Dm);

  // 7) FF2 + bias + residual(h bf16) -> out (fp32)
  gemm8<128, 128, 2, 2, 256, 2, 0, true, 2, false, 0><<<512, 256, 0, stream>>>(
      ff1, w2T, out, b2, hbb, nullptr, BS, Dm, DFm);
}